// Round 1
// baseline (333.674 us; speedup 1.0000x reference)
//
#include <hip/hip_runtime.h>

// HBV 2.0 fused scan + gamma-UH routing, MI355X (gfx950). Round 8.
// R7 = 170us (~560 cyc/step) vs ~200 issue floor. Occupancy is structural
// (313 single-wave blocks); wall = 730 x per-step realized cycles of ONE
// in-order wave. VALUBusy back-solve (~350 exec cy/step >> ~190 static)
// implicates the 4 trans ops (2x log+exp), both on the serial recurrence.
// R8: (1) software-pipeline sw-pow + all input-only precomputes one step
// ahead (only ef's pow stays on-chain); (2) med3 clamps + gw max-form
// (bit-identical); (3) WAIT_VMCNT(29) so chunk stores never gate the next
// chunk's load wait; (4) single chunk-body instantiation + unroll-1 outer
// loop halves I-footprint (~24KB -> ~12KB vs 32KB L1I).

#define TS 730
#define NG 10000
#define CH 15
#define NCHUNK 49            // 49*15 = 735 >= 730
#define XSTRIDE (NG * 3)
#define DSTRIDE (NG * 4)

#define AS1 __attribute__((address_space(1)))
#define AS3 __attribute__((address_space(3)))
// gfx9/CDNA s_waitcnt simm16: vmcnt[3:0]=simm[3:0], vmcnt[5:4]=simm[15:14],
// expcnt=simm[6:4], lgkmcnt=simm[11:8]
#define WAIT_VMCNT(n) __builtin_amdgcn_s_waitcnt(((n) & 15) | 0x70 | 0xF00 | (((n) >> 4) << 14))
#define WAIT_LGKM0    __builtin_amdgcn_s_waitcnt(0xC07F)

__device__ __forceinline__ void gload16(const float* g, float* l) {
    __builtin_amdgcn_global_load_lds((const AS1 void*)g, (AS3 void*)l, 16, 0, 0);
}
// x^b for x>0 via native v_log_f32 + v_exp_f32
__device__ __forceinline__ float powpos(float x, float b) {
    return __builtin_amdgcn_exp2f(b * __builtin_amdgcn_logf(x));
}
// clamp(x, lo, hi) for lo<=hi, finite inputs: identical to min(max(x,lo),hi)
__device__ __forceinline__ float med3(float x, float lo, float hi) {
    return __builtin_amdgcn_fmed3f(x, lo, hi);
}

__global__ __launch_bounds__(64, 1) void hbv_fused(
    const float* __restrict__ x_phy,
    const float* __restrict__ ac_all,
    const float* __restrict__ params_dy,
    const float* __restrict__ params_stat,
    float* __restrict__ out)
{
    // LDS double buffers in exact DMA lane order (lane i -> base + i*16B).
    __shared__ float xls0[1536], xls1[1536];
    __shared__ float dls0[2048], dls1[2048];

    const int lane = threadIdx.x & 63;
    const int m    = lane >> 5;            // nmul component
    const int cell = lane & 31;
    const int g0   = blockIdx.x * 32;
    const int g    = g0 + cell;
    const int gl   = g < NG ? g : NG - 1;
    // last block: shift 32-cell window left so staging never reads OOB
    const int g0r  = (g0 <= NG - 32) ? g0 : NG - 32;
    const int co   = cell + (g0 - g0r);
    const int cl   = co < 31 ? co : 31;    // LDS cell slot (stores masked for dups)

    // ---- static params: params_stat[g, i*2 + m]; routing at 28,29 ----
    const float* ps = params_stat + (size_t)gl * 30;
    const float FC    = ps[0  + m] * 950.f   + 50.f;
    const float K0    = ps[2  + m] * 0.85f   + 0.05f;
    const float K1    = ps[4  + m] * 0.49f   + 0.01f;
    const float K2    = ps[6  + m] * 0.199f  + 0.001f;
    const float LP    = ps[8  + m] * 0.8f    + 0.2f;
    const float PERCp = ps[10 + m] * 10.f;
    const float UZL   = ps[12 + m] * 100.f;
    const float TTp   = ps[14 + m] * 5.f     - 2.5f;
    const float CFMAX = ps[16 + m] * 9.5f    + 0.5f;
    const float CFR   = ps[18 + m] * 0.1f;
    const float CWH   = ps[20 + m] * 0.2f;
    const float Cc    = ps[22 + m];
    const float RT    = ps[24 + m] * 20.f;
    const float ACp   = ps[26 + m] * 2500.f;
    const float ra    = ps[28] * 2.9f;
    const float rb    = ps[29] * 6.5f;

    const float Acv     = ac_all[gl];
    const float invFC   = 1.f / FC;
    const float invLPFC = 1.f / (LP * FC);
    const float CFRC    = CFR * CFMAX;
    const float gwcap   = RT * fminf(fmaxf(1.f - Acv / (ACp + 1e-5f), 0.f), 1.f);

    // ---- UH weights (normalization cancels gammaln/theta^-a prefactor) ----
    const float a     = fmaxf(ra, 0.f) + 0.1f;
    const float th    = fmaxf(rb, 0.f) + 0.5f;
    const float am1   = a - 1.f;
    const float nl2e  = 1.44269504f / th;
    float w[CH];
    float wsum = 0.f;
#pragma unroll
    for (int k = 0; k < CH; ++k) {
        const float tk = (float)k + 0.5f;
        const float v  = __builtin_amdgcn_exp2f(am1 * __builtin_amdgcn_logf(tk) - tk * nl2e);
        w[k] = v; wsum += v;
    }
    const float wn = 0.5f / wsum;  // fold nmul-mean 0.5 into weights
#pragma unroll
    for (int k = 0; k < CH; ++k) w[k] *= wn;

    // ---- per-lane DMA source offsets (float units), chunk-relative ----
    int offx[6], offd[8];
#pragma unroll
    for (int i = 0; i < 6; ++i) {
        int idx = i * 64 + lane;
        idx = idx < 360 ? idx : 359;
        const int row = idx / 24;
        const int col = idx - row * 24;
        offx[i] = row * XSTRIDE + col * 4;
    }
#pragma unroll
    for (int i = 0; i < 8; ++i) {
        int idx = i * 64 + lane;
        idx = idx < 480 ? idx : 479;
        const int row = idx >> 5;
        const int col = idx & 31;
        offd[i] = row * DSTRIDE + col * 4;
    }
    const float* xbase = x_phy     + (size_t)g0r * 3;
    const float* dbase = params_dy + (size_t)g0r * 4;

    auto issue = [&](int cc, float* xl, float* dl) {  // exactly 14 DMA ops
        if (cc == NCHUNK - 1) {
            // last chunk: rows 10..14 would hit t=730..734 -> clamp abs t
#pragma unroll
            for (int i = 0; i < 6; ++i) {
                int idx = i * 64 + lane; idx = idx < 360 ? idx : 359;
                const int row = idx / 24, col = idx - row * 24;
                int t = cc * CH + row; t = t < TS ? t : TS - 1;
                gload16(xbase + (size_t)t * XSTRIDE + col * 4, xl + i * 256);
            }
#pragma unroll
            for (int i = 0; i < 8; ++i) {
                int idx = i * 64 + lane; idx = idx < 480 ? idx : 479;
                const int row = idx >> 5, col = idx & 31;
                int t = cc * CH + row; t = t < TS ? t : TS - 1;
                gload16(dbase + (size_t)t * DSTRIDE + col * 4, dl + i * 256);
            }
        } else {
            const float* xp = xbase + (size_t)cc * CH * XSTRIDE;
            const float* dp = dbase + (size_t)cc * CH * DSTRIDE;
#pragma unroll
            for (int i = 0; i < 6; ++i) gload16(xp + offx[i], xl + i * 256);
#pragma unroll
            for (int i = 0; i < 8; ++i) gload16(dp + offd[i], dl + i * 256);
        }
    };

    // ---- state + per-half routing ring + pipelined carries ----
    float SP = 1e-3f, MW = 1e-3f, SM = 1e-3f, SUZ = 1e-3f, SLZ = 1e-3f;
    float CcSLZ = Cc * SLZ;     // Cc * SLZ_end(prev step), carried
    float facc[CH];
#pragma unroll
    for (int k = 0; k < CH; ++k) facc[k] = 0.f;

    const bool doStore = (g < NG) && (lane < 32);

    auto chunk = [&](int c, const float* xl, const float* dl) {
        float ofl[CH];
        // preload step-0 inputs and derive all input-only values off-chain
        float Pc = xl[cl * 3 + 0], Tc = xl[cl * 3 + 1], Ec = xl[cl * 3 + 2];
        float4 dvc = *(const float4*)&dl[cl * 4];
        const float bc = m ? dvc.y : dvc.x;
        const float ec = m ? dvc.w : dvc.z;
        float SNOWc   = (Tc < TTp) ? Pc : 0.f;
        float rainc   = Pc - SNOWc;
        float mltc    = CFMAX * (Tc - TTp);
        float rfrc    = CFRC * (TTp - Tc);
        float betaetc = fmaf(ec, 4.7f, 0.3f);
        // sw for step 0 from carried SM (same math as ref: min((SM/FC)^beta,1))
        {
            const float beta0 = fmaf(bc, 5.f, 1.f);
            swc_init:;
        }
        float swc;
        {
            const float beta0 = fmaf(bc, 5.f, 1.f);
            swc = fminf(powpos(SM * invFC, beta0), 1.f);
        }
#pragma unroll
        for (int j = 0; j < CH; ++j) {
            float Pn, Tn, En; float4 dvn;
            if (j < CH - 1) {
                Pn  = xl[(j + 1) * 96 + cl * 3 + 0];
                Tn  = xl[(j + 1) * 96 + cl * 3 + 1];
                En  = xl[(j + 1) * 96 + cl * 3 + 2];
                dvn = *(const float4*)&dl[(j + 1) * 128 + cl * 4];
            }
            // ---- snow bucket (med3 == min(max(x,0),cap), bitwise) ----
            SP += SNOWc;
            const float melt = med3(mltc, 0.f, SP);
            MW += melt; SP -= melt;
            const float refr = med3(rfrc, 0.f, MW);
            SP += refr; MW -= refr;
            const float tosoil = fmaxf(MW - CWH * SP, 0.f);
            MW -= tosoil;

            // ---- soil bucket (sw was computed last step, off-chain) ----
            const float rts = rainc + tosoil;
            SM = fmaf(rts, 1.f - swc, SM);
            const float exc = fmaxf(SM - FC, 0.f);
            SM = fminf(SM, FC);
            const float ef = powpos(fminf(SM * invLPFC, 1.f), betaetc);
            const float ET = fminf(SM, Ec * ef);
            SM = fmaxf(SM - ET, 1e-5f);
            // Cc<=1, factor<=1 -> product <= SLZ; reference min is redundant
            const float cap = CcSLZ * (1.f - fminf(SM * invFC, 1.f));
            SM  = fmaxf(SM + cap, 1e-5f);
            SLZ = fmaxf(SLZ - cap, 1e-5f);

            // ---- next-step off-chain precomputes: sw-pow latency hides
            //      under the groundwater chain + routing ring below ----
            float swn = 0.f, betaetn = 0.f, SNOWn = 0.f, rainn = 0.f;
            float mltn = 0.f, rfrn = 0.f;
            if (j < CH - 1) {
                const float bn = m ? dvn.y : dvn.x;
                const float en = m ? dvn.w : dvn.z;
                const float betan = fmaf(bn, 5.f, 1.f);
                betaetn = fmaf(en, 4.7f, 0.3f);
                swn = fminf(powpos(SM * invFC, betan), 1.f);  // SM is final here
                SNOWn = (Tn < TTp) ? Pn : 0.f;
                rainn = Pn - SNOWn;
                mltn  = CFMAX * (Tn - TTp);
                rfrn  = CFRC * (TTp - Tn);
            }

            // ---- groundwater buckets ----
            SUZ += rts * swc + exc;
            const float perc = fminf(SUZ, PERCp);
            SUZ -= perc;
            const float Q0 = K0 * fmaxf(SUZ - UZL, 0.f);
            SUZ -= Q0;
            const float Q1 = K1 * SUZ;
            SUZ -= Q1;
            SLZ += perc;
            SLZ = fmaxf(SLZ - gwcap, 0.f);   // == SLZ - min(SLZ, gwcap), bitwise
            const float Q2 = K2 * SLZ;
            SLZ -= Q2;
            CcSLZ = Cc * SLZ;                // for next step's capillary term
            const float Qt = Q0 + Q1 + Q2;

            // per-half 15-tap UH ring on OWN Qm (cross-half combine batched
            // at epilogue; flow = ring(Qm0) + ring(Qm1) by linearity)
#pragma unroll
            for (int k = 0; k < CH; ++k)
                facc[(j + k) % CH] = fmaf(w[k], Qt, facc[(j + k) % CH]);
            ofl[j]  = facc[j];   // own-half partial flow[t] complete
            facc[j] = 0.f;       // recycle slot for t+15

            if (j < CH - 1) {
                SNOWc = SNOWn; rainc = rainn; mltc = mltn; rfrc = rfrn;
                betaetc = betaetn; swc = swn; Ec = En;
            }
        }
        // epilogue: batched cross-half combine (15 ds_permute, off the chain)
        float prt[CH];
#pragma unroll
        for (int jj = 0; jj < CH; ++jj) prt[jj] = __shfl_xor(ofl[jj], 32);
        // stores BEFORE next issue() so the next chunk's 14 DMAs stay the
        // newest vmcnt entries; WAIT_VMCNT(29) at loop top then allows
        // exactly {15 stores + 14 loads} outstanding (never gates on stores)
        if (doStore) {
            float* op = out + (size_t)c * CH * NG + g;
            const int tb = c * CH;
#pragma unroll
            for (int jj = 0; jj < CH; ++jj)
                if (tb + jj < TS) op[(size_t)jj * NG] = ofl[jj] + prt[jj];
        }
    };

    // prolog: both buffers' DMAs in flight; wait only chunk 0's loads
    issue(0, xls0, dls0);
    issue(1, xls1, dls1);
    WAIT_VMCNT(14);

#pragma unroll 1
    for (int c = 0; c < NCHUNK; ++c) {
        float* xl = (c & 1) ? xls1 : xls0;
        float* dl = (c & 1) ? dls1 : dls0;
        // newest 29 = {15 stores of chunk c-1} + {14 loads of chunk c+1};
        // everything older (incl. chunk c's loads) is forced complete.
        WAIT_VMCNT(29);
        chunk(c, xl, dl);
        WAIT_LGKM0;                        // ds_reads/permutes retired (WAR)
        if (c + 2 < NCHUNK) issue(c + 2, xl, dl);
    }
}

extern "C" void kernel_launch(void* const* d_in, const int* in_sizes, int n_in,
                              void* d_out, int out_size, void* d_ws, size_t ws_size,
                              hipStream_t stream) {
    const float* x_phy = (const float*)d_in[0];
    const float* ac    = (const float*)d_in[1];
    // d_in[2] = elev_all: unused by the reference forward
    const float* pdy   = (const float*)d_in[3];
    const float* pst   = (const float*)d_in[4];
    float* out = (float*)d_out;

    const int grid = (NG + 31) / 32;  // 313 single-wave blocks
    hbv_fused<<<grid, 64, 0, stream>>>(x_phy, ac, pdy, pst, out);
}

// Round 2
// 320.968 us; speedup vs baseline: 1.0396x; 1.0396x over previous
//
#include <hip/hip_runtime.h>

// HBV 2.0 fused scan + gamma-UH routing, MI355X (gfx950). Round 9.
// R7 = 170us dispatch. R8 (body pipelining + med3 + vmcnt(29) + unroll-1
// single-body loop) = 200us, VGPR 104->88, total VALU-busy time unchanged
// -> the unroll-1/runtime-select loop killed the scheduler's cross-chunk
// hoisting window (stall +100 cy/step), not the body changes.
// R9: R7's loop skeleton EXACTLY (two static-buffer chunk instantiations,
// unrolled pair loop) + R8's body-local wins only:
//   (1) sw-pow + all input-only precomputes pipelined one step ahead
//       (only ef's log/exp remains on the serial recurrence);
//   (2) med3 clamps + gw max-form (bit-identical);
//   (3) corrected waits: WAIT_VMCNT(29) in steady state (15 prev stores +
//       14 next loads stay in flight; R7's WAIT(14) forced a store-drain
//       stall every chunk), 14 for chunk 0, 15 before the final chunk.

#define TS 730
#define NG 10000
#define CH 15
#define NCHUNK 49            // 49*15 = 735 >= 730
#define XSTRIDE (NG * 3)
#define DSTRIDE (NG * 4)

#define AS1 __attribute__((address_space(1)))
#define AS3 __attribute__((address_space(3)))
// gfx9/CDNA s_waitcnt simm16: vmcnt[3:0]=simm[3:0], vmcnt[5:4]=simm[15:14],
// expcnt=simm[6:4], lgkmcnt=simm[11:8]
#define WAIT_VMCNT(n) __builtin_amdgcn_s_waitcnt(((n) & 15) | 0x70 | 0xF00 | (((n) >> 4) << 14))
#define WAIT_LGKM0    __builtin_amdgcn_s_waitcnt(0xC07F)

__device__ __forceinline__ void gload16(const float* g, float* l) {
    __builtin_amdgcn_global_load_lds((const AS1 void*)g, (AS3 void*)l, 16, 0, 0);
}
// x^b for x>0 via native v_log_f32 + v_exp_f32
__device__ __forceinline__ float powpos(float x, float b) {
    return __builtin_amdgcn_exp2f(b * __builtin_amdgcn_logf(x));
}
// clamp(x, lo, hi) for lo<=hi, finite inputs: identical to min(max(x,lo),hi)
__device__ __forceinline__ float med3(float x, float lo, float hi) {
    return __builtin_amdgcn_fmed3f(x, lo, hi);
}

__global__ __launch_bounds__(64, 1) void hbv_fused(
    const float* __restrict__ x_phy,
    const float* __restrict__ ac_all,
    const float* __restrict__ params_dy,
    const float* __restrict__ params_stat,
    float* __restrict__ out)
{
    // LDS double buffers in exact DMA lane order (lane i -> base + i*16B).
    __shared__ float xls0[1536], xls1[1536];
    __shared__ float dls0[2048], dls1[2048];

    const int lane = threadIdx.x & 63;
    const int m    = lane >> 5;            // nmul component
    const int cell = lane & 31;
    const int g0   = blockIdx.x * 32;
    const int g    = g0 + cell;
    const int gl   = g < NG ? g : NG - 1;
    // last block: shift 32-cell window left so staging never reads OOB
    const int g0r  = (g0 <= NG - 32) ? g0 : NG - 32;
    const int co   = cell + (g0 - g0r);
    const int cl   = co < 31 ? co : 31;    // LDS cell slot (stores masked for dups)

    // ---- static params: params_stat[g, i*2 + m]; routing at 28,29 ----
    const float* ps = params_stat + (size_t)gl * 30;
    const float FC    = ps[0  + m] * 950.f   + 50.f;
    const float K0    = ps[2  + m] * 0.85f   + 0.05f;
    const float K1    = ps[4  + m] * 0.49f   + 0.01f;
    const float K2    = ps[6  + m] * 0.199f  + 0.001f;
    const float LP    = ps[8  + m] * 0.8f    + 0.2f;
    const float PERCp = ps[10 + m] * 10.f;
    const float UZL   = ps[12 + m] * 100.f;
    const float TTp   = ps[14 + m] * 5.f     - 2.5f;
    const float CFMAX = ps[16 + m] * 9.5f    + 0.5f;
    const float CFR   = ps[18 + m] * 0.1f;
    const float CWH   = ps[20 + m] * 0.2f;
    const float Cc    = ps[22 + m];
    const float RT    = ps[24 + m] * 20.f;
    const float ACp   = ps[26 + m] * 2500.f;
    const float ra    = ps[28] * 2.9f;
    const float rb    = ps[29] * 6.5f;

    const float Acv     = ac_all[gl];
    const float invFC   = 1.f / FC;
    const float invLPFC = 1.f / (LP * FC);
    const float CFRC    = CFR * CFMAX;
    const float gwcap   = RT * fminf(fmaxf(1.f - Acv / (ACp + 1e-5f), 0.f), 1.f);

    // ---- UH weights (normalization cancels gammaln/theta^-a prefactor) ----
    const float a     = fmaxf(ra, 0.f) + 0.1f;
    const float th    = fmaxf(rb, 0.f) + 0.5f;
    const float am1   = a - 1.f;
    const float nl2e  = 1.44269504f / th;
    float w[CH];
    float wsum = 0.f;
#pragma unroll
    for (int k = 0; k < CH; ++k) {
        const float tk = (float)k + 0.5f;
        const float v  = __builtin_amdgcn_exp2f(am1 * __builtin_amdgcn_logf(tk) - tk * nl2e);
        w[k] = v; wsum += v;
    }
    const float wn = 0.5f / wsum;  // fold nmul-mean 0.5 into weights
#pragma unroll
    for (int k = 0; k < CH; ++k) w[k] *= wn;

    // ---- per-lane DMA source offsets (float units), chunk-relative ----
    int offx[6], offd[8];
#pragma unroll
    for (int i = 0; i < 6; ++i) {
        int idx = i * 64 + lane;
        idx = idx < 360 ? idx : 359;
        const int row = idx / 24;
        const int col = idx - row * 24;
        offx[i] = row * XSTRIDE + col * 4;
    }
#pragma unroll
    for (int i = 0; i < 8; ++i) {
        int idx = i * 64 + lane;
        idx = idx < 480 ? idx : 479;
        const int row = idx >> 5;
        const int col = idx & 31;
        offd[i] = row * DSTRIDE + col * 4;
    }
    const float* xbase = x_phy     + (size_t)g0r * 3;
    const float* dbase = params_dy + (size_t)g0r * 4;

    auto issue = [&](int cc, float* xl, float* dl) {  // exactly 14 DMA ops
        if (cc == NCHUNK - 1) {
            // last chunk: rows 10..14 would hit t=730..734 -> clamp abs t
#pragma unroll
            for (int i = 0; i < 6; ++i) {
                int idx = i * 64 + lane; idx = idx < 360 ? idx : 359;
                const int row = idx / 24, col = idx - row * 24;
                int t = cc * CH + row; t = t < TS ? t : TS - 1;
                gload16(xbase + (size_t)t * XSTRIDE + col * 4, xl + i * 256);
            }
#pragma unroll
            for (int i = 0; i < 8; ++i) {
                int idx = i * 64 + lane; idx = idx < 480 ? idx : 479;
                const int row = idx >> 5, col = idx & 31;
                int t = cc * CH + row; t = t < TS ? t : TS - 1;
                gload16(dbase + (size_t)t * DSTRIDE + col * 4, dl + i * 256);
            }
        } else {
            const float* xp = xbase + (size_t)cc * CH * XSTRIDE;
            const float* dp = dbase + (size_t)cc * CH * DSTRIDE;
#pragma unroll
            for (int i = 0; i < 6; ++i) gload16(xp + offx[i], xl + i * 256);
#pragma unroll
            for (int i = 0; i < 8; ++i) gload16(dp + offd[i], dl + i * 256);
        }
    };

    // ---- state + per-half routing ring + pipelined carry ----
    float SP = 1e-3f, MW = 1e-3f, SM = 1e-3f, SUZ = 1e-3f, SLZ = 1e-3f;
    float CcSLZ = Cc * SLZ;     // Cc * SLZ_end(prev step), carried
    float facc[CH];
#pragma unroll
    for (int k = 0; k < CH; ++k) facc[k] = 0.f;

    const bool doStore = (g < NG) && (lane < 32);

    auto chunk = [&](int c, const float* xl, const float* dl) {
        float ofl[CH];
        // step-0 inputs; all input-only derivations computed off-chain here
        float Ec, SNOWc, rainc, mltc, rfrc, betaetc, swc;
        {
            const float Pc = xl[cl * 3 + 0];
            const float Tc = xl[cl * 3 + 1];
            Ec = xl[cl * 3 + 2];
            const float4 dvc = *(const float4*)&dl[cl * 4];
            const float bc = m ? dvc.y : dvc.x;
            const float ec = m ? dvc.w : dvc.z;
            SNOWc = (Tc < TTp) ? Pc : 0.f;
            rainc = Pc - SNOWc;
            mltc  = CFMAX * (Tc - TTp);
            rfrc  = CFRC * (TTp - Tc);
            betaetc = fmaf(ec, 4.7f, 0.3f);
            const float beta0 = fmaf(bc, 5.f, 1.f);
            // sw uses SM carried from previous step: min((SM/FC)^beta, 1)
            swc = fminf(powpos(SM * invFC, beta0), 1.f);
        }
#pragma unroll
        for (int j = 0; j < CH; ++j) {
            // ---- snow bucket (med3 == min(max(x,0),cap), bitwise) ----
            SP += SNOWc;
            const float melt = med3(mltc, 0.f, SP);
            MW += melt; SP -= melt;
            const float refr = med3(rfrc, 0.f, MW);
            SP += refr; MW -= refr;
            const float tosoil = fmaxf(MW - CWH * SP, 0.f);
            MW -= tosoil;

            // ---- soil bucket (sw was computed last step, off-chain) ----
            const float rts = rainc + tosoil;
            SM = fmaf(rts, 1.f - swc, SM);
            const float exc = fmaxf(SM - FC, 0.f);
            SM = fminf(SM, FC);
            const float ef = powpos(fminf(SM * invLPFC, 1.f), betaetc);
            const float ET = fminf(SM, Ec * ef);
            SM = fmaxf(SM - ET, 1e-5f);
            // Cc<=1, factor<=1 -> product <= SLZ; reference min is redundant
            const float cap = CcSLZ * (1.f - fminf(SM * invFC, 1.f));
            SM  = fmaxf(SM + cap, 1e-5f);
            SLZ = fmaxf(SLZ - cap, 1e-5f);

            // ---- next-step off-chain precomputes: sw-pow latency hides
            //      under the groundwater chain + routing ring below ----
            float swn = 0.f, betaetn = 0.f, SNOWn = 0.f, rainn = 0.f;
            float mltn = 0.f, rfrn = 0.f, En = 0.f;
            if (j < CH - 1) {
                const float Pn  = xl[(j + 1) * 96 + cl * 3 + 0];
                const float Tn  = xl[(j + 1) * 96 + cl * 3 + 1];
                En              = xl[(j + 1) * 96 + cl * 3 + 2];
                const float4 dvn = *(const float4*)&dl[(j + 1) * 128 + cl * 4];
                const float bn = m ? dvn.y : dvn.x;
                const float en = m ? dvn.w : dvn.z;
                const float betan = fmaf(bn, 5.f, 1.f);
                betaetn = fmaf(en, 4.7f, 0.3f);
                swn = fminf(powpos(SM * invFC, betan), 1.f);  // SM final here
                SNOWn = (Tn < TTp) ? Pn : 0.f;
                rainn = Pn - SNOWn;
                mltn  = CFMAX * (Tn - TTp);
                rfrn  = CFRC * (TTp - Tn);
            }

            // ---- groundwater buckets ----
            SUZ += rts * swc + exc;
            const float perc = fminf(SUZ, PERCp);
            SUZ -= perc;
            const float Q0 = K0 * fmaxf(SUZ - UZL, 0.f);
            SUZ -= Q0;
            const float Q1 = K1 * SUZ;
            SUZ -= Q1;
            SLZ += perc;
            SLZ = fmaxf(SLZ - gwcap, 0.f);   // == SLZ - min(SLZ, gwcap), bitwise
            const float Q2 = K2 * SLZ;
            SLZ -= Q2;
            CcSLZ = Cc * SLZ;                // for next step's capillary term
            const float Qt = Q0 + Q1 + Q2;

            // per-half 15-tap UH ring on OWN Qm (cross-half combine batched
            // at epilogue; flow = ring(Qm0) + ring(Qm1) by linearity)
#pragma unroll
            for (int k = 0; k < CH; ++k)
                facc[(j + k) % CH] = fmaf(w[k], Qt, facc[(j + k) % CH]);
            ofl[j]  = facc[j];   // own-half partial flow[t] complete
            facc[j] = 0.f;       // recycle slot for t+15

            if (j < CH - 1) {
                SNOWc = SNOWn; rainc = rainn; mltc = mltn; rfrc = rfrn;
                betaetc = betaetn; swc = swn; Ec = En;
            }
        }
        // epilogue: batched cross-half combine (15 ds_permute, off the chain)
        float prt[CH];
#pragma unroll
        for (int jj = 0; jj < CH; ++jj) prt[jj] = __shfl_xor(ofl[jj], 32);
        // stores BEFORE next issue() so the next chunk's 14 DMAs stay the
        // newest vmcnt entries; steady-state WAIT_VMCNT(29) then allows
        // exactly {15 prev stores + 14 next loads} to stay outstanding
        if (doStore) {
            float* op = out + (size_t)c * CH * NG + g;
            const int tb = c * CH;
#pragma unroll
            for (int jj = 0; jj < CH; ++jj)
                if (tb + jj < TS) op[(size_t)jj * NG] = ofl[jj] + prt[jj];
        }
    };

    // prolog: both buffers' DMAs in flight
    issue(0, xls0, dls0);
    issue(1, xls1, dls1);

    // chunk 0: only 28 loads outstanding -> need WAIT(14) to drain loads(0)
    WAIT_VMCNT(14);
    chunk(0, xls0, dls0);
    WAIT_LGKM0;                            // ds_reads/permutes retired (WAR)
    issue(2, xls0, dls0);
    // chunk 1: outstanding = loads(1)[14] + stores(0)[15] + loads(2)[14]
    WAIT_VMCNT(29);                        // drain loads(1), stores stay
    chunk(1, xls1, dls1);
    WAIT_LGKM0;
    issue(3, xls1, dls1);

    // steady state: chunks 2..47 in pairs, R7's two-instantiation skeleton
    for (int cp = 1; cp < 24; ++cp) {
        const int c0 = 2 * cp;
        // outstanding: loads(c0)[14] + stores(c0-1)[15] + loads(c0+1)[14]
        WAIT_VMCNT(29);                    // drain loads(c0) only
        chunk(c0, xls0, dls0);
        WAIT_LGKM0;
        issue(c0 + 2, xls0, dls0);         // up to issue(48)
        WAIT_VMCNT(29);                    // drain loads(c0+1) only
        chunk(c0 + 1, xls1, dls1);
        WAIT_LGKM0;
        if (cp < 23) issue(c0 + 3, xls1, dls1);  // up to issue(47)
    }
    // outstanding: stores(46)[15] + loads(48)[14] + stores(47)[15] = 44;
    // leave only stores(47) -> loads(48) drained
    WAIT_VMCNT(15);
    chunk(48, xls0, dls0);
}

extern "C" void kernel_launch(void* const* d_in, const int* in_sizes, int n_in,
                              void* d_out, int out_size, void* d_ws, size_t ws_size,
                              hipStream_t stream) {
    const float* x_phy = (const float*)d_in[0];
    const float* ac    = (const float*)d_in[1];
    // d_in[2] = elev_all: unused by the reference forward
    const float* pdy   = (const float*)d_in[3];
    const float* pst   = (const float*)d_in[4];
    float* out = (float*)d_out;

    const int grid = (NG + 31) / 32;  // 313 single-wave blocks
    hbv_fused<<<grid, 64, 0, stream>>>(x_phy, ac, pdy, pst, out);
}

// Round 3
// 300.772 us; speedup vs baseline: 1.1094x; 1.0671x over previous
//
#include <hip/hip_runtime.h>

// HBV 2.0 fused scan + gamma-UH routing, MI355X (gfx950). Round 10.
// History: R7=170us (pair skeleton, per-step ds_reads). R8=200, R9=226:
// both moved next-step ds_reads into a mid-body precompute block with
// read-to-use ~5 instructions -> ~120cy exposed DS latency per step.
// Total VALU-busy time constant across R7/R8/R9 (~32us) => all deltas are
// stall; the body's read placement is the lever, not the skeleton.
// R10: batch ALL 30 LDS reads of a chunk at chunk top into registers
// (105 VGPR, free at 1 wave/SIMD), one lgkmcnt(0) + sched_barrier(0) pin,
// then a pure-ALU 15-step body with ZERO ds ops. issue(c+2) moves to just
// after the read block (WAR-safe: inputs are in regs), which makes uniform
// WAIT_VMCNT(27) exempt the previous chunk's stores (they are among the 27
// newest) -> R7's per-chunk store-drain stall also gone. Body math is R7's
// exactly; med3/gw-max forms are bit-identical.

#define TS 730
#define NG 10000
#define CH 15
#define NCHUNK 49            // 49*15 = 735 >= 730
#define XSTRIDE (NG * 3)
#define DSTRIDE (NG * 4)

#define AS1 __attribute__((address_space(1)))
#define AS3 __attribute__((address_space(3)))
// gfx9/CDNA s_waitcnt simm16: vmcnt[3:0]=simm[3:0], vmcnt[5:4]=simm[15:14],
// expcnt=simm[6:4], lgkmcnt=simm[11:8]
#define WAIT_VMCNT(n) __builtin_amdgcn_s_waitcnt(((n) & 15) | 0x70 | 0xF00 | (((n) >> 4) << 14))
#define WAIT_LGKM0    __builtin_amdgcn_s_waitcnt(0xC07F)

__device__ __forceinline__ void gload16(const float* g, float* l) {
    __builtin_amdgcn_global_load_lds((const AS1 void*)g, (AS3 void*)l, 16, 0, 0);
}
// x^b for x>0 via native v_log_f32 + v_exp_f32
__device__ __forceinline__ float powpos(float x, float b) {
    return __builtin_amdgcn_exp2f(b * __builtin_amdgcn_logf(x));
}
// clamp(x, lo, hi) for lo<=hi, finite inputs: identical to min(max(x,lo),hi)
__device__ __forceinline__ float med3(float x, float lo, float hi) {
    return __builtin_amdgcn_fmed3f(x, lo, hi);
}

__global__ __launch_bounds__(64, 1) void hbv_fused(
    const float* __restrict__ x_phy,
    const float* __restrict__ ac_all,
    const float* __restrict__ params_dy,
    const float* __restrict__ params_stat,
    float* __restrict__ out)
{
    // LDS double buffers in exact DMA lane order (lane i -> base + i*16B).
    __shared__ float xls0[1536], xls1[1536];
    __shared__ float dls0[2048], dls1[2048];

    const int lane = threadIdx.x & 63;
    const int m    = lane >> 5;            // nmul component
    const int cell = lane & 31;
    const int g0   = blockIdx.x * 32;
    const int g    = g0 + cell;
    const int gl   = g < NG ? g : NG - 1;
    // last block: shift 32-cell window left so staging never reads OOB
    const int g0r  = (g0 <= NG - 32) ? g0 : NG - 32;
    const int co   = cell + (g0 - g0r);
    const int cl   = co < 31 ? co : 31;    // LDS cell slot (stores masked for dups)

    // ---- static params: params_stat[g, i*2 + m]; routing at 28,29 ----
    const float* ps = params_stat + (size_t)gl * 30;
    const float FC    = ps[0  + m] * 950.f   + 50.f;
    const float K0    = ps[2  + m] * 0.85f   + 0.05f;
    const float K1    = ps[4  + m] * 0.49f   + 0.01f;
    const float K2    = ps[6  + m] * 0.199f  + 0.001f;
    const float LP    = ps[8  + m] * 0.8f    + 0.2f;
    const float PERCp = ps[10 + m] * 10.f;
    const float UZL   = ps[12 + m] * 100.f;
    const float TTp   = ps[14 + m] * 5.f     - 2.5f;
    const float CFMAX = ps[16 + m] * 9.5f    + 0.5f;
    const float CFR   = ps[18 + m] * 0.1f;
    const float CWH   = ps[20 + m] * 0.2f;
    const float Cc    = ps[22 + m];
    const float RT    = ps[24 + m] * 20.f;
    const float ACp   = ps[26 + m] * 2500.f;
    const float ra    = ps[28] * 2.9f;
    const float rb    = ps[29] * 6.5f;

    const float Acv     = ac_all[gl];
    const float invFC   = 1.f / FC;
    const float invLPFC = 1.f / (LP * FC);
    const float CFRC    = CFR * CFMAX;
    const float gwcap   = RT * fminf(fmaxf(1.f - Acv / (ACp + 1e-5f), 0.f), 1.f);

    // ---- UH weights (normalization cancels gammaln/theta^-a prefactor) ----
    const float a     = fmaxf(ra, 0.f) + 0.1f;
    const float th    = fmaxf(rb, 0.f) + 0.5f;
    const float am1   = a - 1.f;
    const float nl2e  = 1.44269504f / th;
    float w[CH];
    float wsum = 0.f;
#pragma unroll
    for (int k = 0; k < CH; ++k) {
        const float tk = (float)k + 0.5f;
        const float v  = __builtin_amdgcn_exp2f(am1 * __builtin_amdgcn_logf(tk) - tk * nl2e);
        w[k] = v; wsum += v;
    }
    const float wn = 0.5f / wsum;  // fold nmul-mean 0.5 into weights
#pragma unroll
    for (int k = 0; k < CH; ++k) w[k] *= wn;

    // ---- per-lane DMA source offsets (float units), chunk-relative ----
    int offx[6], offd[8];
#pragma unroll
    for (int i = 0; i < 6; ++i) {
        int idx = i * 64 + lane;
        idx = idx < 360 ? idx : 359;
        const int row = idx / 24;
        const int col = idx - row * 24;
        offx[i] = row * XSTRIDE + col * 4;
    }
#pragma unroll
    for (int i = 0; i < 8; ++i) {
        int idx = i * 64 + lane;
        idx = idx < 480 ? idx : 479;
        const int row = idx >> 5;
        const int col = idx & 31;
        offd[i] = row * DSTRIDE + col * 4;
    }
    const float* xbase = x_phy     + (size_t)g0r * 3;
    const float* dbase = params_dy + (size_t)g0r * 4;

    auto issue = [&](int cc, float* xl, float* dl) {  // exactly 14 DMA ops
        if (cc == NCHUNK - 1) {
            // last chunk: rows 10..14 would hit t=730..734 -> clamp abs t
#pragma unroll
            for (int i = 0; i < 6; ++i) {
                int idx = i * 64 + lane; idx = idx < 360 ? idx : 359;
                const int row = idx / 24, col = idx - row * 24;
                int t = cc * CH + row; t = t < TS ? t : TS - 1;
                gload16(xbase + (size_t)t * XSTRIDE + col * 4, xl + i * 256);
            }
#pragma unroll
            for (int i = 0; i < 8; ++i) {
                int idx = i * 64 + lane; idx = idx < 480 ? idx : 479;
                const int row = idx >> 5, col = idx & 31;
                int t = cc * CH + row; t = t < TS ? t : TS - 1;
                gload16(dbase + (size_t)t * DSTRIDE + col * 4, dl + i * 256);
            }
        } else {
            const float* xp = xbase + (size_t)cc * CH * XSTRIDE;
            const float* dp = dbase + (size_t)cc * CH * DSTRIDE;
#pragma unroll
            for (int i = 0; i < 6; ++i) gload16(xp + offx[i], xl + i * 256);
#pragma unroll
            for (int i = 0; i < 8; ++i) gload16(dp + offd[i], dl + i * 256);
        }
    };

    // ---- state + routing ring ----
    float SP = 1e-3f, MW = 1e-3f, SM = 1e-3f, SUZ = 1e-3f, SLZ = 1e-3f;
    float facc[CH];
#pragma unroll
    for (int k = 0; k < CH; ++k) facc[k] = 0.f;

    const bool doStore = (g < NG) && (lane < 32);

    auto chunkR = [&](int c, float* xl, float* dl) {
        // ---- batched input reads -> registers, pinned at chunk top ----
        float xP[CH], xT[CH], xE[CH];
        float4 dv[CH];
#pragma unroll
        for (int j = 0; j < CH; ++j) {
            xP[j] = xl[j * 96 + cl * 3 + 0];
            xT[j] = xl[j * 96 + cl * 3 + 1];
            xE[j] = xl[j * 96 + cl * 3 + 2];
            dv[j] = *(const float4*)&dl[j * 128 + cl * 4];
        }
        WAIT_LGKM0;                          // all 30 reads retired to regs
        __builtin_amdgcn_sched_barrier(0);   // pin: no read sinks below here
        // ---- prefetch next chunk's DMAs (WAR-safe: inputs are in regs) ----
        const int cn = c + 2;
        if (cn < NCHUNK) issue(cn, xl, dl);
        // ---- pure-register 15-step body (zero DS ops) ----
        float ofl[CH];
#pragma unroll
        for (int j = 0; j < CH; ++j) {
            const float Pt = xP[j], Tt = xT[j], PETt = xE[j];
            const float beta   = (m ? dv[j].y : dv[j].x) * 5.f  + 1.f;
            const float betaet = (m ? dv[j].w : dv[j].z) * 4.7f + 0.3f;

            // snow bucket (med3 == min(max(x,0),cap), bit-identical)
            const float rain = (Tt >= TTp) ? Pt : 0.f;
            SP += Pt - rain;
            const float melt = med3(CFMAX * (Tt - TTp), 0.f, SP);
            MW += melt; SP -= melt;
            const float refr = med3(CFRC * (TTp - Tt), 0.f, MW);
            SP += refr; MW -= refr;
            const float tosoil = fmaxf(MW - CWH * SP, 0.f);
            MW -= tosoil;

            // soil bucket (SM > 0 strictly: native log safe)
            const float sw  = fminf(powpos(SM * invFC, beta), 1.f);
            const float rts = rain + tosoil;
            SM = fmaf(rts, 1.f - sw, SM);
            const float exc = fmaxf(SM - FC, 0.f);
            SM = fminf(SM, FC);
            const float ef = powpos(fminf(SM * invLPFC, 1.f), betaet);
            const float ET = fminf(SM, PETt * ef);
            SM = fmaxf(SM - ET, 1e-5f);
            // Cc<=1, factor<=1 -> product <= SLZ; reference min is redundant
            const float cap = Cc * SLZ * (1.f - fminf(SM * invFC, 1.f));
            SM  = fmaxf(SM + cap, 1e-5f);
            SLZ = fmaxf(SLZ - cap, 1e-5f);

            // groundwater buckets
            SUZ += rts * sw + exc;
            const float perc = fminf(SUZ, PERCp);
            SUZ -= perc;
            const float Q0 = K0 * fmaxf(SUZ - UZL, 0.f);
            SUZ -= Q0;
            const float Q1 = K1 * SUZ;
            SUZ -= Q1;
            SLZ += perc;
            SLZ = fmaxf(SLZ - gwcap, 0.f);   // == SLZ - min(SLZ,gwcap), bitwise
            const float Q2 = K2 * SLZ;
            SLZ -= Q2;
            const float Qt = Q0 + Q1 + Q2;

            // per-half 15-tap UH ring on OWN Qm (cross-half combine batched
            // at epilogue; flow = ring(Qm0) + ring(Qm1) by linearity)
#pragma unroll
            for (int k = 0; k < CH; ++k)
                facc[(j + k) % CH] = fmaf(w[k], Qt, facc[(j + k) % CH]);
            ofl[j]  = facc[j];   // own-half partial flow[t] complete
            facc[j] = 0.f;       // recycle slot for t+15
        }
        // epilogue: batched cross-half combine (15 ds_permute, off the chain)
        float prt[CH];
#pragma unroll
        for (int jj = 0; jj < CH; ++jj) prt[jj] = __shfl_xor(ofl[jj], 32);
        // stores last: they become part of the "27 newest" VM ops at the
        // next chunk's WAIT_VMCNT(27) and are never force-drained.
        if (doStore) {
            float* op = out + (size_t)c * CH * NG + g;
            const int tb = c * CH;
#pragma unroll
            for (int jj = 0; jj < CH; ++jj)
                if (tb + jj < TS) op[(size_t)jj * NG] = ofl[jj] + prt[jj];
        }
        __builtin_amdgcn_sched_barrier(0);   // pin stores before next WAIT
    };

    // prolog: both buffers' DMAs in flight
    issue(0, xls0, dls0);
    issue(1, xls1, dls1);

    // Uniform WAIT_VMCNT(27) everywhere:
    //  c=0: 54 outstanding -> leaves loads(1), drains loads(0). OK.
    //  steady c: [loads(c), stores(c-2), loads(c+1), stores(c-1)] ->
    //    newest 27 = stores(c-1)[15] + newest 12 of loads(c+1); drains
    //    loads(c) (required), stores(c-2) + older 15 of loads(c+1) (both
    //    ~a full chunk old, already retired). Fresh stores never drained.
    //  c=48: newest 27 = stores(47)[15] + 12 of stores(46); drains loads(48).
    for (int cp = 0; cp < 24; ++cp) {
        const int c0 = 2 * cp;
        WAIT_VMCNT(27);
        chunkR(c0, xls0, dls0);        // issues c0+2 inside
        WAIT_VMCNT(27);
        chunkR(c0 + 1, xls1, dls1);    // issues c0+3 inside (guarded)
    }
    WAIT_VMCNT(27);
    chunkR(48, xls0, dls0);            // cn=50 -> no issue
}

extern "C" void kernel_launch(void* const* d_in, const int* in_sizes, int n_in,
                              void* d_out, int out_size, void* d_ws, size_t ws_size,
                              hipStream_t stream) {
    const float* x_phy = (const float*)d_in[0];
    const float* ac    = (const float*)d_in[1];
    // d_in[2] = elev_all: unused by the reference forward
    const float* pdy   = (const float*)d_in[3];
    const float* pst   = (const float*)d_in[4];
    float* out = (float*)d_out;

    const int grid = (NG + 31) / 32;  // 313 single-wave blocks
    hbv_fused<<<grid, 64, 0, stream>>>(x_phy, ac, pdy, pst, out);
}